// Round 11
// baseline (145.114 us; speedup 1.0000x reference)
//
#include <hip/hip_runtime.h>
#include <cstdint>
#include <cstddef>

namespace {

constexpr int Bn   = 8;
constexpr int Cc   = 128;
constexpr int Hh   = 56;
constexpr int Ww   = 56;
constexpr int OUTC = 128;
constexpr int NTAP = 9;
constexpr int HW   = 3136;
constexpr int NPOS = Bn * HW;      // 25088
constexpr int KDIM = 1152;         // Cc*NTAP
constexpr int CH   = Bn * 18 * HW; // partial chunk stride (451584 floats)

constexpr int PT   = 32;           // K2 positions per block
constexpr int CCH  = 64;           // K2 channels per chunk (2 chunks)
constexpr int KC   = CCH * NTAP;   // 576
constexpr int LROW = 584;          // ushort row stride (1168B, 16B-aligned)
constexpr int NTILE = NPOS / PT;   // 784

constexpr int OFFBLK = 1568;       // K1: offset-conv blocks
constexpr int WBLK   = 576;        // K1: cwb relayout blocks

typedef __attribute__((ext_vector_type(8))) short  short8v;
typedef __attribute__((ext_vector_type(4))) short  short4v;
typedef __attribute__((ext_vector_type(4))) float  float4v;

__device__ __forceinline__ unsigned short f2bf(float f) {
    union { float f; uint32_t u; } v; v.f = f;
    const uint32_t u = v.u;
    return (unsigned short)((u + 0x7fffu + ((u >> 16) & 1u)) >> 16);  // RNE
}
__device__ __forceinline__ float bf2f(unsigned short us) {
    union { uint32_t u; float f; } v; v.u = (uint32_t)us << 16;
    return v.f;
}

// ---------------------------------------------------------------------------
// K1: verbatim R4 (best measured, 125.0us total). Fused offset-conv partials
// + cwb relayout + xt transpose.
// Block ranges:
//   [0, 1568)            offset-conv chunk partials (4 chunks x 32ch)
//   [1568, 2144)         cwb bf16 fragment-contiguous relayout
//   [2144, 2536)         x -> xt bf16 plane transpose [b][g16][ij][8ch]
// ---------------------------------------------------------------------------
__global__ __launch_bounds__(256) void fused_prep_offset_kernel(
        const float* __restrict__ x, const float* __restrict__ ow,
        const float* __restrict__ cw,
        unsigned short* __restrict__ cwb, unsigned short* __restrict__ xt,
        float* __restrict__ partial) {
    __shared__ float red[4][64 * 18];              // 18.4 KB (offset path only)

    const int blk = blockIdx.x;
    const int t   = threadIdx.x;

    if (blk >= OFFBLK) {
        const int pb = blk - OFFBLK;
        if (pb < WBLK) {                           // weights: 128*1152 elems
            const int i = pb * 256 + t;
            // decompose by cwb layout: i = (((cc*18+ks)*8+wv)*64 + mm*4+quad)*8 + u
            const int u   = i & 7;
            const int mq  = (i >> 3) & 63;         // mm*4+quad
            const int wvv = (i >> 9) & 7;
            const int rest = i >> 12;              // 0..35
            const int ks = rest % 18, ccg = rest / 18;
            const int mm = mq >> 2, quad = mq & 3;
            const int klocal = ks * 32 + quad * 8 + u;
            const int n = klocal >> 6, cl = klocal & 63;
            const int o = wvv * 16 + mm;
            cwb[i] = f2bf(cw[o * KDIM + (ccg * CCH + cl) * NTAP + n]);
            return;
        }
        // transpose: 392 blocks, 64 pos x 128 ch each -> plane layout
        const int pb2 = pb - WBLK;
        const int b = pb2 & 7;
        const int ijb = (pb2 >> 3) * 64;
        const int lp2 = t & 63, cg = t >> 6;
        const float* xb = x + (size_t)b * Cc * HW + ijb + lp2;
#pragma unroll
        for (int c8 = 0; c8 < 4; ++c8) {
            short8v sv;
#pragma unroll
            for (int u = 0; u < 8; ++u)
                sv[u] = (short)f2bf(xb[(size_t)(cg * 32 + c8 * 8 + u) * HW]);
            const int g16 = cg * 4 + c8;
            *(short8v*)(xt + ((size_t)(b * 16 + g16) * HW + ijb + lp2) * 8) = sv;
        }
        return;
    }

    // ---- offset-conv chunk partials (identical math to R2/R4) ----
    const int lane = t & 63;
    const int sq   = __builtin_amdgcn_readfirstlane(t >> 6);   // wave-uniform slice
    const int chunk = blk & 3;                     // 32-c chunk
    const int pgi  = blk >> 2;
    const int b    = pgi & 7;
    const int ijb  = (pgi >> 3) * 64;
    const int ij   = ijb + lane;
    const int i    = ij / Ww, j = ij % Ww;
    const float* xb = x + (size_t)b * Cc * HW;

    float acc[18];
#pragma unroll
    for (int m = 0; m < 18; ++m) acc[m] = 0.f;

    const int c0 = chunk * 32 + sq * 8;
    for (int cc = 0; cc < 8; ++cc) {
        const int c = c0 + cc;
        const float* xc = xb + (size_t)c * HW;
        float xv[9];
#pragma unroll
        for (int ky = 0; ky < 3; ++ky) {
            const int y = i + ky - 1;
            const bool yv = (unsigned)y < (unsigned)Hh;
#pragma unroll
            for (int kx = 0; kx < 3; ++kx) {
                const int xx = j + kx - 1;
                xv[ky * 3 + kx] = (yv && (unsigned)xx < (unsigned)Ww) ? xc[y * Ww + xx] : 0.f;
            }
        }
        const float* wc = ow + c * NTAP;           // wave-uniform scalar loads
#pragma unroll
        for (int m = 0; m < 18; ++m) {
#pragma unroll
            for (int tap = 0; tap < 9; ++tap)
                acc[m] = fmaf(wc[m * KDIM + tap], xv[tap], acc[m]);
        }
    }

#pragma unroll
    for (int m = 0; m < 18; ++m) red[sq][lane * 18 + m] = acc[m];
    __syncthreads();

    // ---- m-outer store order (R4): coalesced 64x4B per wave-inst ----
    float* pout = partial + (size_t)chunk * CH;
    for (int e = t; e < 64 * 18; e += 256) {
        const int m = e >> 6, lpe = e & 63;        // wave: one m, 64 consecutive ij
        const int idx = lpe * 18 + m;
        const float s01 = red[0][idx] + red[1][idx];
        const float s23 = red[2][idx] + red[3][idx];
        pout[(size_t)(b * 18 + m) * HW + ijb + lpe] = s01 + s23;
    }
}

// ---------------------------------------------------------------------------
// K2: R11 DIAGNOSTIC (R10 hardened) — body verbatim R2/R4, grid doubled;
// duplicate blocks (blk >= NTILE) do ALL the work but SKIP the final store
// (runtime block-uniform predicate — compiler keeps the compute since the
// store is on the shared path). No write races, rocprof replay fully
// deterministic. Purpose: push this dispatch to ~76us, above the 43us fill
// cutoff, for its first post-R2 counters. Discriminator: VALUBusy>=50% ->
// repack issue-bound; VALUBusy 20-30% + small FETCH -> latency/barrier-bound
// (-> T14 double-buffer next); FETCH >~25MB -> L2 locality; conflicts >~3M
// -> LDS swizzle.
// ---------------------------------------------------------------------------
__global__ __launch_bounds__(512, 6) void deform_mfma_kernel(
        const unsigned short* __restrict__ xt, const unsigned short* __restrict__ cwb,
        const float* __restrict__ partial, const float* __restrict__ ob,
        float* __restrict__ out) {
    __shared__ unsigned short xoffB[PT * LROW];    // 36.5 KB
    __shared__ float4v pgS[PT * NTAP];             // {g2,g3,g0,g1}  4.6 KB
    __shared__ int2    poS[PT * NTAP];             // {o2|o3<<16, o0|o1<<16}

    const int t    = threadIdx.x;
    const int lane = t & 63;
    const int mm   = lane & 15, quad = lane >> 4;
    const int wv   = t >> 6;                       // 0..7: 16 out-ch each
    const int lp   = t & 31;                       // staging: pos
    const int grp  = (t >> 5) & 7;                 // staging: 8-ch group
    const int nh   = t >> 8;                       // staging: tap parity (wave-uniform)
    int blk = blockIdx.x;
    const bool dup = (blk >= NTILE);               // diagnostic duplicate block
    if (dup) blk -= NTILE;
    const int b    = blk & 7;                      // XCD affinity
    const int ijb  = (blk >> 3) * PT;
    const unsigned short* xtb = xt + (size_t)b * 16 * HW * 8;   // per-b plane base

    // ---- params: inline 4-partial combine, then exact fp32 chain ----
    for (int e = t; e < PT * NTAP; e += 512) {
        const int n = e >> 5, lpe = e & 31;
        const int ij = ijb + lpe;
        const size_t iy = (size_t)(b * 18 + n) * HW + ij;
        const size_t ix = (size_t)(b * 18 + 9 + n) * HW + ij;
        float sy = (partial[iy] + partial[CH + iy]) + (partial[2 * CH + iy] + partial[3 * CH + iy]);
        float sx = (partial[ix] + partial[CH + ix]) + (partial[2 * CH + ix] + partial[3 * CH + ix]);
        sy = sy + ob[n];
        sx = sx + ob[9 + n];
        const float py = (float)(ij / Ww + n / 3) + sy;
        const float px = (float)(ij % Ww + n % 3) + sx;
        const float q0y = floorf(py), q0x = floorf(px);
        const float lty = fminf(fmaxf(q0y, 0.f), 57.f);
        const float ltx = fminf(fmaxf(q0x, 0.f), 57.f);
        const float rby = fminf(fmaxf(q0y + 1.f, 0.f), 57.f);
        const float rbx = fminf(fmaxf(q0x + 1.f, 0.f), 57.f);
        const float pyc = fminf(fmaxf(py, 0.f), 57.f);
        const float pxc = fminf(fmaxf(px, 0.f), 57.f);
        float g0 = (1.f - (pyc - lty)) * truncf(1.f - (pxc - ltx));   // lt
        float g1 = (1.f - (rby - pyc)) * truncf(1.f - (rbx - pxc));   // rb
        float g2 = (1.f - (pyc - lty)) * (1.f - (rbx - pxc));         // lb (lty,rbx)
        float g3 = (1.f - (rby - pyc)) * (1.f - (pxc - ltx));         // rt (rby,ltx)
        const int y0 = (int)lty - 1, x0 = (int)ltx - 1;
        const int y1 = (int)rby - 1, x1 = (int)rbx - 1;
        const bool v0y = (unsigned)y0 < (unsigned)Hh, v0x = (unsigned)x0 < (unsigned)Ww;
        const bool v1y = (unsigned)y1 < (unsigned)Hh, v1x = (unsigned)x1 < (unsigned)Ww;
        int o0 = y0 * Ww + x0, o1 = y1 * Ww + x1, o2 = y0 * Ww + x1, o3 = y1 * Ww + x0;
        if (!(v0y && v0x)) { o0 = 0; g0 = 0.f; }
        if (!(v1y && v1x)) { o1 = 0; g1 = 0.f; }
        if (!(v0y && v1x)) { o2 = 0; g2 = 0.f; }
        if (!(v1y && v0x)) { o3 = 0; g3 = 0.f; }
        pgS[e] = (float4v){ g2, g3, g0, g1 };
        poS[e] = make_int2((o2 & 0xffff) | (o3 << 16), (o0 & 0xffff) | (o1 << 16));
    }

    float4v acc[2] = { {0.f,0.f,0.f,0.f}, {0.f,0.f,0.f,0.f} };
    __syncthreads();

    for (int cc = 0; cc < 2; ++cc) {
        if (cc) __syncthreads();
        // ---- branchless staging from xt planes; taps split across halves ----
        const unsigned short* pl = xtb + (size_t)(cc * 8 + grp) * HW * 8;
#pragma unroll
        for (int nn = 0; nn < 5; ++nn) {
            const int n = nn * 2 + nh;             // nh=0: 0,2,4,6,8  nh=1: 1,3,5,7
            if (n < 9) {
                const float4v G = pgS[n * 32 + lp];
                const int2  O = poS[n * 32 + lp];
                const short8v a0 = *(const short8v*)(pl + (size_t)(O.y & 0xffff) * 8);
                const short8v a2 = *(const short8v*)(pl + (size_t)(O.x & 0xffff) * 8);
                const short8v a3 = *(const short8v*)(pl + (size_t)((O.x >> 16) & 0xffff) * 8);
                const short8v a1 = *(const short8v*)(pl + (size_t)((O.y >> 16) & 0xffff) * 8);
                short8v sv;
#pragma unroll
                for (int u = 0; u < 8; ++u) {
                    float v = G.x * bf2f((unsigned short)a2[u]);
                    v = fmaf(G.y, bf2f((unsigned short)a3[u]), v);
                    v = fmaf(G.z, bf2f((unsigned short)a0[u]), v);
                    v = fmaf(G.w, bf2f((unsigned short)a1[u]), v);
                    sv[u] = (short)f2bf(v);
                }
                *(short8v*)&xoffB[lp * LROW + n * CCH + grp * 8] = sv;
            }
        }
        __syncthreads();

        // ---- MFMA GEMM: 18 ks-steps, B from contiguous 1KB streams ----
        const unsigned short* bw = cwb + (size_t)(cc * 144 + wv) * 512 + (mm * 4 + quad) * 8;
        const unsigned short* ap0 = &xoffB[mm * LROW + quad * 8];
#pragma unroll 3
        for (int ks = 0; ks < KC / 32; ++ks) {
            const int kl = ks * 32;
            const short8v b0 = *(const short8v*)(bw + ks * 4096);
#pragma unroll
            for (int pt = 0; pt < 2; ++pt) {
                const unsigned short* ap = ap0 + pt * 16 * LROW + kl;
                const short4v alo = *(const short4v*)ap;
                const short4v ahi = *(const short4v*)(ap + 4);
                const short8v a = __builtin_shufflevector(alo, ahi, 0, 1, 2, 3, 4, 5, 6, 7);
                acc[pt] = __builtin_amdgcn_mfma_f32_16x16x32_bf16(a, b0, acc[pt], 0, 0, 0);
            }
        }
    }

    // ---- epilogue (rows wv*16+mm); duplicate blocks skip the store ----
    if (!dup) {
        float* ob0 = out + (size_t)(b * OUTC + wv * 16 + mm) * HW + ijb + quad * 4;
#pragma unroll
        for (int pt = 0; pt < 2; ++pt)
            *(float4v*)(ob0 + pt * 16) = acc[pt];
    }
}

}  // namespace

extern "C" void kernel_launch(void* const* d_in, const int* in_sizes, int n_in,
                              void* d_out, int out_size, void* d_ws, size_t ws_size,
                              hipStream_t stream) {
    const float* x  = (const float*)d_in[0];   // (8,128,56,56)
    const float* ow = (const float*)d_in[1];   // (18,128,3,3)
    const float* ob = (const float*)d_in[2];   // (18,)
    const float* cw = (const float*)d_in[3];   // (128,128,3,3)
    float* out = (float*)d_out;                // (8,128,56,56)

    char* wsp = (char*)d_ws;
    unsigned short* cwb = (unsigned short*)wsp;                 //    294,912 B
    unsigned short* xt = (unsigned short*)(wsp + 294912);       //  6,422,528 B
    float* partial = (float*)(wsp + 6717440);                   //  7,225,344 B (4 chunks)
                                                                // total 13.94 MB

    fused_prep_offset_kernel<<<OFFBLK + WBLK + 392, 256, 0, stream>>>(
        x, ow, cw, cwb, xt, partial);
    deform_mfma_kernel<<<2 * NTILE, 512, 0, stream>>>(xt, cwb, partial, ob, out);  // rep=2 diag
}

// Round 12
// 126.544 us; speedup vs baseline: 1.1467x; 1.1467x over previous
//
#include <hip/hip_runtime.h>
#include <cstdint>
#include <cstddef>

namespace {

constexpr int Bn   = 8;
constexpr int Cc   = 128;
constexpr int Hh   = 56;
constexpr int Ww   = 56;
constexpr int OUTC = 128;
constexpr int NTAP = 9;
constexpr int HW   = 3136;
constexpr int NPOS = Bn * HW;      // 25088
constexpr int KDIM = 1152;         // Cc*NTAP
constexpr int CH   = Bn * 18 * HW; // partial chunk stride (451584 floats)

constexpr int PT   = 32;           // K2 positions per block
constexpr int CCH  = 64;           // K2 channels per chunk (2 chunks)
constexpr int KC   = CCH * NTAP;   // 576
constexpr int LROW = 584;          // ushort row stride (1168B, 16B-aligned)
constexpr int NTILE = NPOS / PT;   // 784

constexpr int OFFBLK = 1568;       // K1: offset-conv blocks
constexpr int WBLK   = 576;        // K1: cwb relayout blocks

typedef __attribute__((ext_vector_type(8))) short  short8v;
typedef __attribute__((ext_vector_type(4))) float  float4v;

__device__ __forceinline__ unsigned short f2bf(float f) {
    union { float f; uint32_t u; } v; v.f = f;
    const uint32_t u = v.u;
    return (unsigned short)((u + 0x7fffu + ((u >> 16) & 1u)) >> 16);  // RNE
}
__device__ __forceinline__ float bf2f(unsigned short us) {
    union { uint32_t u; float f; } v; v.u = (uint32_t)us << 16;
    return v.f;
}

// ---------------------------------------------------------------------------
// K1: verbatim R4 (best measured). Fused offset-conv partials + cwb relayout
// + xt transpose.
// Block ranges:
//   [0, 1568)            offset-conv chunk partials (4 chunks x 32ch)
//   [1568, 2144)         cwb bf16 fragment-contiguous relayout
//   [2144, 2536)         x -> xt bf16 plane transpose [b][g16][ij][8ch]
// ---------------------------------------------------------------------------
__global__ __launch_bounds__(256) void fused_prep_offset_kernel(
        const float* __restrict__ x, const float* __restrict__ ow,
        const float* __restrict__ cw,
        unsigned short* __restrict__ cwb, unsigned short* __restrict__ xt,
        float* __restrict__ partial) {
    __shared__ float red[4][64 * 18];              // 18.4 KB (offset path only)

    const int blk = blockIdx.x;
    const int t   = threadIdx.x;

    if (blk >= OFFBLK) {
        const int pb = blk - OFFBLK;
        if (pb < WBLK) {                           // weights: 128*1152 elems
            const int i = pb * 256 + t;
            // decompose by cwb layout: i = (((cc*18+ks)*8+wv)*64 + mm*4+quad)*8 + u
            const int u   = i & 7;
            const int mq  = (i >> 3) & 63;         // mm*4+quad
            const int wvv = (i >> 9) & 7;
            const int rest = i >> 12;              // 0..35
            const int ks = rest % 18, ccg = rest / 18;
            const int mm = mq >> 2, quad = mq & 3;
            const int klocal = ks * 32 + quad * 8 + u;
            const int n = klocal >> 6, cl = klocal & 63;
            const int o = wvv * 16 + mm;
            cwb[i] = f2bf(cw[o * KDIM + (ccg * CCH + cl) * NTAP + n]);
            return;
        }
        // transpose: 392 blocks, 64 pos x 128 ch each -> plane layout
        const int pb2 = pb - WBLK;
        const int b = pb2 & 7;
        const int ijb = (pb2 >> 3) * 64;
        const int lp2 = t & 63, cg = t >> 6;
        const float* xb = x + (size_t)b * Cc * HW + ijb + lp2;
#pragma unroll
        for (int c8 = 0; c8 < 4; ++c8) {
            short8v sv;
#pragma unroll
            for (int u = 0; u < 8; ++u)
                sv[u] = (short)f2bf(xb[(size_t)(cg * 32 + c8 * 8 + u) * HW]);
            const int g16 = cg * 4 + c8;
            *(short8v*)(xt + ((size_t)(b * 16 + g16) * HW + ijb + lp2) * 8) = sv;
        }
        return;
    }

    // ---- offset-conv chunk partials (identical math to R2/R4) ----
    const int lane = t & 63;
    const int sq   = __builtin_amdgcn_readfirstlane(t >> 6);   // wave-uniform slice
    const int chunk = blk & 3;                     // 32-c chunk
    const int pgi  = blk >> 2;
    const int b    = pgi & 7;
    const int ijb  = (pgi >> 3) * 64;
    const int ij   = ijb + lane;
    const int i    = ij / Ww, j = ij % Ww;
    const float* xb = x + (size_t)b * Cc * HW;

    float acc[18];
#pragma unroll
    for (int m = 0; m < 18; ++m) acc[m] = 0.f;

    const int c0 = chunk * 32 + sq * 8;
    for (int cc = 0; cc < 8; ++cc) {
        const int c = c0 + cc;
        const float* xc = xb + (size_t)c * HW;
        float xv[9];
#pragma unroll
        for (int ky = 0; ky < 3; ++ky) {
            const int y = i + ky - 1;
            const bool yv = (unsigned)y < (unsigned)Hh;
#pragma unroll
            for (int kx = 0; kx < 3; ++kx) {
                const int xx = j + kx - 1;
                xv[ky * 3 + kx] = (yv && (unsigned)xx < (unsigned)Ww) ? xc[y * Ww + xx] : 0.f;
            }
        }
        const float* wc = ow + c * NTAP;           // wave-uniform scalar loads
#pragma unroll
        for (int m = 0; m < 18; ++m) {
#pragma unroll
            for (int tap = 0; tap < 9; ++tap)
                acc[m] = fmaf(wc[m * KDIM + tap], xv[tap], acc[m]);
        }
    }

#pragma unroll
    for (int m = 0; m < 18; ++m) red[sq][lane * 18 + m] = acc[m];
    __syncthreads();

    // ---- m-outer store order (R4): coalesced 64x4B per wave-inst ----
    float* pout = partial + (size_t)chunk * CH;
    for (int e = t; e < 64 * 18; e += 256) {
        const int m = e >> 6, lpe = e & 63;        // wave: one m, 64 consecutive ij
        const int idx = lpe * 18 + m;
        const float s01 = red[0][idx] + red[1][idx];
        const float s23 = red[2][idx] + red[3][idx];
        pout[(size_t)(b * 18 + m) * HW + ijb + lpe] = s01 + s23;
    }
}

// ---------------------------------------------------------------------------
// K2 v4 (R12). R11 counters: VALUBusy 34%, MfmaUtil 10%, FETCH small ->
// mixed VALU + exposed-L2-latency. Three co-designed fixes:
//  (1) staging: 1-deep gather prefetch (tap t+1's 4 loads issued before tap
//      t's combine; +16 VGPR, occupancy unchanged — LDS caps 3 blocks/CU);
//  (2) staging output via v_cvt_pk_bf16_f32 (RNE, same as f2bf bit-trick):
//      8 manual conversions (~24 ops) -> 4 insts, staging VALU -20%;
//  (3) ks-loop unroll 6 (6 b0 L2 loads in flight vs 3) + A-fragment as one
//      aligned b128 LDS read (LROW*2=1168 = 16B-aligned rows).
// Math order per element identical to R4 -> same output bits (normals).
// ---------------------------------------------------------------------------
__global__ __launch_bounds__(512, 6) void deform_mfma_kernel(
        const unsigned short* __restrict__ xt, const unsigned short* __restrict__ cwb,
        const float* __restrict__ partial, const float* __restrict__ ob,
        float* __restrict__ out) {
    __shared__ unsigned short xoffB[PT * LROW];    // 36.5 KB
    __shared__ float4v pgS[PT * NTAP];             // {g2,g3,g0,g1}  4.6 KB
    __shared__ int2    poS[PT * NTAP];             // {o2|o3<<16, o0|o1<<16}

    const int t    = threadIdx.x;
    const int lane = t & 63;
    const int mm   = lane & 15, quad = lane >> 4;
    const int wv   = t >> 6;                       // 0..7: 16 out-ch each
    const int lp   = t & 31;                       // staging: pos
    const int grp  = (t >> 5) & 7;                 // staging: 8-ch group
    const int nh   = t >> 8;                       // staging: tap parity (wave-uniform)
    const int blk  = blockIdx.x;
    const int b    = blk & 7;                      // XCD affinity
    const int ijb  = (blk >> 3) * PT;
    const unsigned short* xtb = xt + (size_t)b * 16 * HW * 8;   // per-b plane base

    // ---- params: inline 4-partial combine, then exact fp32 chain ----
    for (int e = t; e < PT * NTAP; e += 512) {
        const int n = e >> 5, lpe = e & 31;
        const int ij = ijb + lpe;
        const size_t iy = (size_t)(b * 18 + n) * HW + ij;
        const size_t ix = (size_t)(b * 18 + 9 + n) * HW + ij;
        float sy = (partial[iy] + partial[CH + iy]) + (partial[2 * CH + iy] + partial[3 * CH + iy]);
        float sx = (partial[ix] + partial[CH + ix]) + (partial[2 * CH + ix] + partial[3 * CH + ix]);
        sy = sy + ob[n];
        sx = sx + ob[9 + n];
        const float py = (float)(ij / Ww + n / 3) + sy;
        const float px = (float)(ij % Ww + n % 3) + sx;
        const float q0y = floorf(py), q0x = floorf(px);
        const float lty = fminf(fmaxf(q0y, 0.f), 57.f);
        const float ltx = fminf(fmaxf(q0x, 0.f), 57.f);
        const float rby = fminf(fmaxf(q0y + 1.f, 0.f), 57.f);
        const float rbx = fminf(fmaxf(q0x + 1.f, 0.f), 57.f);
        const float pyc = fminf(fmaxf(py, 0.f), 57.f);
        const float pxc = fminf(fmaxf(px, 0.f), 57.f);
        float g0 = (1.f - (pyc - lty)) * truncf(1.f - (pxc - ltx));   // lt
        float g1 = (1.f - (rby - pyc)) * truncf(1.f - (rbx - pxc));   // rb
        float g2 = (1.f - (pyc - lty)) * (1.f - (rbx - pxc));         // lb (lty,rbx)
        float g3 = (1.f - (rby - pyc)) * (1.f - (pxc - ltx));         // rt (rby,ltx)
        const int y0 = (int)lty - 1, x0 = (int)ltx - 1;
        const int y1 = (int)rby - 1, x1 = (int)rbx - 1;
        const bool v0y = (unsigned)y0 < (unsigned)Hh, v0x = (unsigned)x0 < (unsigned)Ww;
        const bool v1y = (unsigned)y1 < (unsigned)Hh, v1x = (unsigned)x1 < (unsigned)Ww;
        int o0 = y0 * Ww + x0, o1 = y1 * Ww + x1, o2 = y0 * Ww + x1, o3 = y1 * Ww + x0;
        if (!(v0y && v0x)) { o0 = 0; g0 = 0.f; }
        if (!(v1y && v1x)) { o1 = 0; g1 = 0.f; }
        if (!(v0y && v1x)) { o2 = 0; g2 = 0.f; }
        if (!(v1y && v0x)) { o3 = 0; g3 = 0.f; }
        pgS[e] = (float4v){ g2, g3, g0, g1 };
        poS[e] = make_int2((o2 & 0xffff) | (o3 << 16), (o0 & 0xffff) | (o1 << 16));
    }

    float4v acc[2] = { {0.f,0.f,0.f,0.f}, {0.f,0.f,0.f,0.f} };
    __syncthreads();

    for (int cc = 0; cc < 2; ++cc) {
        if (cc) __syncthreads();
        // ---- staging: 1-deep prefetched tap pipeline, cvt_pk output ----
        const unsigned short* pl = xtb + (size_t)(cc * 8 + grp) * HW * 8;
        const int NT = 5 - nh;                     // wave-uniform tap count
        int n = nh;
        float4v G = pgS[n * 32 + lp];
        int2 O = poS[n * 32 + lp];
        short8v a0 = *(const short8v*)(pl + (size_t)(O.y & 0xffff) * 8);
        short8v a2 = *(const short8v*)(pl + (size_t)(O.x & 0xffff) * 8);
        short8v a3 = *(const short8v*)(pl + (size_t)((O.x >> 16) & 0xffff) * 8);
        short8v a1 = *(const short8v*)(pl + (size_t)((O.y >> 16) & 0xffff) * 8);
        for (int tt = 0; tt < NT; ++tt) {
            const bool more = (tt + 1 < NT);
            float4v Gn; int2 On;
            short8v p0, p1, p2, p3;
            if (more) {                            // issue next tap's gathers NOW
                Gn = pgS[(n + 2) * 32 + lp];
                On = poS[(n + 2) * 32 + lp];
                p0 = *(const short8v*)(pl + (size_t)(On.y & 0xffff) * 8);
                p2 = *(const short8v*)(pl + (size_t)(On.x & 0xffff) * 8);
                p3 = *(const short8v*)(pl + (size_t)((On.x >> 16) & 0xffff) * 8);
                p1 = *(const short8v*)(pl + (size_t)((On.y >> 16) & 0xffff) * 8);
            }
            float v[8];
#pragma unroll
            for (int u = 0; u < 8; ++u) {
                float vv = G.x * bf2f((unsigned short)a2[u]);
                vv = fmaf(G.y, bf2f((unsigned short)a3[u]), vv);
                vv = fmaf(G.z, bf2f((unsigned short)a0[u]), vv);
                vv = fmaf(G.w, bf2f((unsigned short)a1[u]), vv);
                v[u] = vv;
            }
            uint32_t d0, d1, d2, d3;               // RNE pack, 2 f32 -> 1 dword
            asm("v_cvt_pk_bf16_f32 %0, %1, %2" : "=v"(d0) : "v"(v[0]), "v"(v[1]));
            asm("v_cvt_pk_bf16_f32 %0, %1, %2" : "=v"(d1) : "v"(v[2]), "v"(v[3]));
            asm("v_cvt_pk_bf16_f32 %0, %1, %2" : "=v"(d2) : "v"(v[4]), "v"(v[5]));
            asm("v_cvt_pk_bf16_f32 %0, %1, %2" : "=v"(d3) : "v"(v[6]), "v"(v[7]));
            *(int4*)&xoffB[lp * LROW + n * CCH + grp * 8] =
                make_int4((int)d0, (int)d1, (int)d2, (int)d3);
            if (more) { G = Gn; O = On; a0 = p0; a1 = p1; a2 = p2; a3 = p3; n += 2; }
        }
        __syncthreads();

        // ---- MFMA GEMM: 18 ks-steps, 6-deep b0 pipeline, b128 A-reads ----
        const unsigned short* bw = cwb + (size_t)(cc * 144 + wv) * 512 + (mm * 4 + quad) * 8;
        const unsigned short* ap0 = &xoffB[mm * LROW + quad * 8];
#pragma unroll 6
        for (int ks = 0; ks < KC / 32; ++ks) {
            const int kl = ks * 32;
            const short8v b0 = *(const short8v*)(bw + ks * 4096);
#pragma unroll
            for (int pt = 0; pt < 2; ++pt) {
                const short8v a = *(const short8v*)(ap0 + pt * 16 * LROW + kl);
                acc[pt] = __builtin_amdgcn_mfma_f32_16x16x32_bf16(a, b0, acc[pt], 0, 0, 0);
            }
        }
    }

    // ---- epilogue (rows wv*16+mm, layout verified) ----
    float* ob0 = out + (size_t)(b * OUTC + wv * 16 + mm) * HW + ijb + quad * 4;
#pragma unroll
    for (int pt = 0; pt < 2; ++pt)
        *(float4v*)(ob0 + pt * 16) = acc[pt];
}

}  // namespace

extern "C" void kernel_launch(void* const* d_in, const int* in_sizes, int n_in,
                              void* d_out, int out_size, void* d_ws, size_t ws_size,
                              hipStream_t stream) {
    const float* x  = (const float*)d_in[0];   // (8,128,56,56)
    const float* ow = (const float*)d_in[1];   // (18,128,3,3)
    const float* ob = (const float*)d_in[2];   // (18,)
    const float* cw = (const float*)d_in[3];   // (128,128,3,3)
    float* out = (float*)d_out;                // (8,128,56,56)

    char* wsp = (char*)d_ws;
    unsigned short* cwb = (unsigned short*)wsp;                 //    294,912 B
    unsigned short* xt = (unsigned short*)(wsp + 294912);       //  6,422,528 B
    float* partial = (float*)(wsp + 6717440);                   //  7,225,344 B (4 chunks)
                                                                // total 13.94 MB

    fused_prep_offset_kernel<<<OFFBLK + WBLK + 392, 256, 0, stream>>>(
        x, ow, cw, cwb, xt, partial);
    deform_mfma_kernel<<<NTILE, 512, 0, stream>>>(xt, cwb, partial, ob, out);
}